// Round 7
// baseline (699.554 us; speedup 1.0000x reference)
//
#include <hip/hip_runtime.h>
#include <math.h>
#include <limits.h>

#define DIM 2048
#define NEXP 256
#define TOPK 8
#define BM 16
#define BK 16
#define NTH 256
#define NTILE (DIM / BK)   // 128 k-tiles

// np-einsum fp32 replica (LOCKED by R3/R4/R6 passes — do not perturb):
//   4 partial chains per output, chain j takes k ≡ j (mod 4);
//   k in 16-groups ascending, within group chunk order 3,2,1,0;
//   separate mul/add rounding (no fma); hadd tree (l0+l1)+(l2+l3);
//   sigmoid in f64 -> f32; pairwise-8 weight sum; ties -> lower index.

__device__ __forceinline__ void gload16(const void* gptr, void* lptr) {
    __builtin_amdgcn_global_load_lds(
        (const __attribute__((address_space(1))) unsigned int*)(unsigned long long)gptr,
        (__attribute__((address_space(3))) unsigned int*)(unsigned int)(unsigned long long)lptr,
        16, 0, 0);
}

// H = which LDS buffer (compile-time -> all addresses base+imm)
template <int H>
__device__ __forceinline__ void compute_half(float (&acc)[4][4][4],
                                             const float* __restrict__ wrd,
                                             const float* __restrict__ xrd)
{
#pragma clang fp contract(off)
#pragma unroll
    for (int c = 3; c >= 0; --c) {          // reversed chunk order in 16-group
        float4 xv[4];
#pragma unroll
        for (int r = 0; r < 4; ++r)
            xv[r] = *(const float4*)&xrd[H * 256 + r * 16 + c * 4];   // broadcast
#pragma unroll
        for (int i = 0; i < 4; ++i) {
            const float4 wv = *(const float4*)&wrd[H * 4096 + c * 1024 + i * 256];
#pragma unroll
            for (int r = 0; r < 4; ++r) {
                acc[r][i][0] = acc[r][i][0] + xv[r].x * wv.x;
                acc[r][i][1] = acc[r][i][1] + xv[r].y * wv.y;
                acc[r][i][2] = acc[r][i][2] + xv[r].z * wv.z;
                acc[r][i][3] = acc[r][i][3] + xv[r].w * wv.w;
            }
        }
    }
}

__global__ __launch_bounds__(NTH) void gate_kernel(
    const float* __restrict__ x, const float* __restrict__ w,
    const float* __restrict__ bias, float* __restrict__ outw,
    float* __restrict__ outi)
{
#pragma clang fp contract(off)
    // wbuf[buf]: float idx (c*256 + e)*4 + j  (chunk c=0..3, expert e, j=k%4)
    __shared__ float wbuf[2][4096];   // 32 KB
    __shared__ float xbuf[2][256];    // 2 KB  [row*16 + k]

    const int tid   = threadIdx.x;
    const int elane = tid & 63;              // experts elane + 64*i
    const int r0    = (tid >> 6) * 4;        // 4 rows per thread
    const int gr    = blockIdx.x * BM;

    // ---- staging sources (pointer-incremented, imm-folded offsets) ----
    const char* wsrc = (const char*)w + (size_t)tid * (DIM * 4);  // expert row `tid`
    const int xrow = tid >> 2, xq = tid & 3;                      // tid<64 stages x
    const char* xsrc = (const char*)x + ((size_t)(gr + xrow) * DIM + xq * 4) * 4;

    // ---- staging LDS dests (loop-invariant) ----
    char* wdst0 = (char*)&wbuf[0][0] + tid * 16;
    char* wdst1 = (char*)&wbuf[1][0] + tid * 16;
    char* xdst0 = (char*)&xbuf[0][0] + tid * 16;
    char* xdst1 = (char*)&xbuf[1][0] + tid * 16;

    // ---- read bases (single VGPR each; everything else is imm) ----
    const float* wrd = &wbuf[0][elane * 4];
    const float* xrd = &xbuf[0][r0 * 16];

#define STAGE_W(DST, KOFF) do {                       \
        gload16(wsrc + (KOFF),      (DST));           \
        gload16(wsrc + (KOFF) + 16, (DST) + 4096);    \
        gload16(wsrc + (KOFF) + 32, (DST) + 8192);    \
        gload16(wsrc + (KOFF) + 48, (DST) + 12288);   \
    } while (0)

    float acc[4][4][4];                      // [row r][expert i][chain j]
#pragma unroll
    for (int r = 0; r < 4; ++r)
#pragma unroll
        for (int i = 0; i < 4; ++i)
#pragma unroll
            for (int j = 0; j < 4; ++j) acc[r][i][j] = 0.0f;

    // ---- main loop: double-buffered, 2-tile unrolled (compile-time buf) ----
    STAGE_W(wdst0, 0);
    if (tid < 64) gload16(xsrc, xdst0);
    __syncthreads();

    for (int it = 0; it < 63; ++it) {
        STAGE_W(wdst1, 64);
        if (tid < 64) gload16(xsrc + 64, xdst1);
        compute_half<0>(acc, wrd, xrd);
        __syncthreads();

        wsrc += 128; xsrc += 128;
        STAGE_W(wdst0, 0);
        if (tid < 64) gload16(xsrc, xdst0);
        compute_half<1>(acc, wrd, xrd);
        __syncthreads();
    }
    // tiles 126 (buf0 already staged) and 127
    STAGE_W(wdst1, 64);
    if (tid < 64) gload16(xsrc + 64, xdst1);
    compute_half<0>(acc, wrd, xrd);
    __syncthreads();
    compute_half<1>(acc, wrd, xrd);
    // no barrier needed: sc region (wbuf[0]) is disjoint from buf1/xbuf reads

    // ---- epilogue: hadd tree + f64 sigmoid -> scores in wbuf[0] ----
    float* sc = &wbuf[0][0];                 // [16][256] = 16 KB (exact fit)
#pragma unroll
    for (int r = 0; r < 4; ++r)
#pragma unroll
        for (int i = 0; i < 4; ++i) {
            const float l01 = acc[r][i][0] + acc[r][i][1];
            const float l23 = acc[r][i][2] + acc[r][i][3];
            const float logit = l01 + l23;
            const double s = 1.0 / (1.0 + exp(-(double)logit));
            sc[(r0 + r) * NEXP + (elane + 64 * i)] = (float)s;
        }
    __syncthreads();

    float* cval = &wbuf[1][0];               // [16][64]
    int*   cidx = (int*)&wbuf[1][1024];      // [16][64]

    // ---- per-row top-8: 8 subs/row on first 128 threads ----
    if (tid < 128) {
        const int row = tid >> 3;
        const int sub = tid & 7;
        float tv[TOPK];
        int   ti[TOPK];
#pragma unroll
        for (int q = 0; q < TOPK; ++q) { tv[q] = -INFINITY; ti[q] = INT_MAX; }
        for (int j = 0; j < 32; ++j) {
            const int e = sub + (j << 3);    // ascending index => stable
            const float v = sc[row * NEXP + e] + bias[e];
            if (v > tv[TOPK - 1]) {
                int p = TOPK - 1;
                while (p > 0 && v > tv[p - 1]) {
                    tv[p] = tv[p - 1]; ti[p] = ti[p - 1]; --p;
                }
                tv[p] = v; ti[p] = e;
            }
        }
#pragma unroll
        for (int q = 0; q < TOPK; ++q) {
            cval[row * 64 + sub * 8 + q] = tv[q];
            cidx[row * 64 + sub * 8 + q] = ti[q];
        }
    }
    __syncthreads();

    // ---- leaders merge 8 sorted lists; ties -> lower index; output ----
    if (tid < 128 && (tid & 7) == 0) {
        const int row = tid >> 3;
        int p[8];
#pragma unroll
        for (int s = 0; s < 8; ++s) p[s] = 0;
        float g[TOPK];
        int   sel[TOPK];
        for (int k = 0; k < TOPK; ++k) {
            float best = -INFINITY;
            int bidx = INT_MAX;
            int bs = 0;
            for (int s = 0; s < 8; ++s) {
                if (p[s] < 8) {
                    const float v = cval[row * 64 + s * 8 + p[s]];
                    const int  id = cidx[row * 64 + s * 8 + p[s]];
                    if (v > best || (v == best && id < bidx)) {
                        best = v; bidx = id; bs = s;
                    }
                }
            }
            p[bs]++;
            sel[k] = bidx;
            g[k] = sc[row * NEXP + bidx];    // original score (no bias)
        }
        const float s01 = g[0] + g[1], s23 = g[2] + g[3];
        const float s45 = g[4] + g[5], s67 = g[6] + g[7];
        const float wsum = (s01 + s23) + (s45 + s67);
        const float den = wsum + 1e-20f;
        const size_t orow = (size_t)(gr + row) * TOPK;
#pragma unroll
        for (int k = 0; k < TOPK; ++k) {
            outw[orow + k] = (g[k] / den) * 2.5f;
            outi[orow + k] = (float)sel[k];
        }
    }
#undef STAGE_W
}

extern "C" void kernel_launch(void* const* d_in, const int* in_sizes, int n_in,
                              void* d_out, int out_size, void* d_ws, size_t ws_size,
                              hipStream_t stream) {
    const float* x    = (const float*)d_in[0];
    const float* w    = (const float*)d_in[1];
    const float* bias = (const float*)d_in[2];
    float* outw = (float*)d_out;
    const int M = in_sizes[0] / DIM;              // 16384 rows
    float* outi = outw + (size_t)M * TOPK;
    const int grid = M / BM;                      // 1024 blocks
    hipLaunchKernelGGL(gate_kernel, dim3(grid), dim3(NTH), 0, stream,
                       x, w, bias, outw, outi);
}

// Round 8
// 464.171 us; speedup vs baseline: 1.5071x; 1.5071x over previous
//
#include <hip/hip_runtime.h>
#include <math.h>
#include <limits.h>

#define DIM 2048
#define NEXP 256
#define TOPK 8
#define BM 16
#define BK 16
#define NTH 256
#define NTILE (DIM / BK)   // 128 k-tiles

// np-einsum fp32 replica (LOCKED by R3/R4/R6 passes — do not perturb):
//   4 partial chains per output, chain j takes k ≡ j (mod 4);
//   k in 16-groups ascending, within group chunk order 3,2,1,0;
//   separate mul/add rounding (no fma); hadd tree (l0+l1)+(l2+l3);
//   sigmoid in f64 -> f32; pairwise-8 weight sum; ties -> lower index.
// v_pk_mul_f32 / v_pk_add_f32 are element-wise IEEE f32 mul/add (VOP3P dual
// issue) -> bit-identical to scalar chain, half the issue cycles.
// R7 lesson: keep VGPR <= ~96 (occupancy), no manual unroll/macro staging.

typedef float f32x2 __attribute__((ext_vector_type(2)));

__device__ __forceinline__ f32x2 pkmul(f32x2 a, f32x2 b) {
    f32x2 d;
    asm("v_pk_mul_f32 %0, %1, %2" : "=v"(d) : "v"(a), "v"(b));
    return d;
}
__device__ __forceinline__ f32x2 pkadd(f32x2 a, f32x2 b) {
    f32x2 d;
    asm("v_pk_add_f32 %0, %1, %2" : "=v"(d) : "v"(a), "v"(b));
    return d;
}

__device__ __forceinline__ void gload16(const void* gptr, void* lptr) {
    __builtin_amdgcn_global_load_lds(
        (const __attribute__((address_space(1))) unsigned int*)(unsigned long long)gptr,
        (__attribute__((address_space(3))) unsigned int*)(unsigned int)(unsigned long long)lptr,
        16, 0, 0);
}

__global__ __launch_bounds__(NTH) void gate_kernel(
    const float* __restrict__ x, const float* __restrict__ w,
    const float* __restrict__ bias, float* __restrict__ outw,
    float* __restrict__ outi)
{
#pragma clang fp contract(off)
    // wbuf[buf]: float idx (c*256 + e)*4 + j  (chunk c=0..3, expert e, j=k%4)
    __shared__ float wbuf[2][4096];   // 32 KB
    __shared__ float xbuf[2][256];    // 2 KB  [row*16 + k]

    const int tid   = threadIdx.x;
    const int elane = tid & 63;              // experts elane + 64*i
    const int r0    = (tid >> 6) * 4;        // 4 rows per thread
    const int gr    = blockIdx.x * BM;

    const char* wbase = (const char*)w + (size_t)tid * (DIM * 4);   // expert row `tid`
    const int xrow = tid >> 2, xq = tid & 3;                        // tid<64 stages x
    const char* xbase = (const char*)x + ((size_t)(gr + xrow) * DIM + xq * 4) * 4;

    auto stage = [&](int buf, int kt) {
        const size_t kb = (size_t)kt * 64;   // 16 floats per tile = 64 B
#pragma unroll
        for (int c = 0; c < 4; ++c)
            gload16(wbase + kb + c * 16, (char*)&wbuf[buf][0] + c * 4096 + tid * 16);
        if (tid < 64)
            gload16(xbase + kb, (char*)&xbuf[buf][0] + tid * 16);
    };

    // acc[r][i][p]: p=0 -> chains (j0,j1), p=1 -> chains (j2,j3)
    f32x2 acc[4][4][2];
#pragma unroll
    for (int r = 0; r < 4; ++r)
#pragma unroll
        for (int i = 0; i < 4; ++i)
#pragma unroll
            for (int p = 0; p < 2; ++p) acc[r][i][p] = (f32x2){0.0f, 0.0f};

    auto compute = [&](int buf) {
#pragma unroll
        for (int c = 3; c >= 0; --c) {          // reversed chunk order in 16-group
            f32x2 xlo[4], xhi[4];
#pragma unroll
            for (int r = 0; r < 4; ++r) {
                const float4 xv = *(const float4*)&xbuf[buf][(r0 + r) * BK + c * 4];
                xlo[r] = (f32x2){xv.x, xv.y};
                xhi[r] = (f32x2){xv.z, xv.w};
            }
#pragma unroll
            for (int i = 0; i < 4; ++i) {
                const float4 wv = *(const float4*)&wbuf[buf][(c * 256 + elane + 64 * i) * 4];
                const f32x2 wlo = (f32x2){wv.x, wv.y};
                const f32x2 whi = (f32x2){wv.z, wv.w};
#pragma unroll
                for (int r = 0; r < 4; ++r) {
                    acc[r][i][0] = pkadd(acc[r][i][0], pkmul(xlo[r], wlo));
                    acc[r][i][1] = pkadd(acc[r][i][1], pkmul(xhi[r], whi));
                }
            }
        }
    };

    // ---- main loop: double-buffered global_load_lds pipeline ----
    stage(0, 0);
    __syncthreads();
    for (int kt = 0; kt < NTILE; ++kt) {
        const int buf = kt & 1;
        if (kt + 1 < NTILE) stage(buf ^ 1, kt + 1);
        compute(buf);
        __syncthreads();
    }

    // ---- epilogue: hadd tree + f64 sigmoid -> scores in wbuf[0] ----
    float* sc = &wbuf[0][0];                 // [16][256] = 16 KB (exact fit)
#pragma unroll
    for (int r = 0; r < 4; ++r)
#pragma unroll
        for (int i = 0; i < 4; ++i) {
            const float l01 = acc[r][i][0].x + acc[r][i][0].y;
            const float l23 = acc[r][i][1].x + acc[r][i][1].y;
            const float logit = l01 + l23;
            const double s = 1.0 / (1.0 + exp(-(double)logit));
            sc[(r0 + r) * NEXP + (elane + 64 * i)] = (float)s;
        }
    __syncthreads();

    float* cval = &wbuf[1][0];               // [16][64]
    int*   cidx = (int*)&wbuf[1][1024];      // [16][64]

    // ---- per-row top-8: 8 subs/row on first 128 threads ----
    if (tid < 128) {
        const int row = tid >> 3;
        const int sub = tid & 7;
        float tv[TOPK];
        int   ti[TOPK];
#pragma unroll
        for (int q = 0; q < TOPK; ++q) { tv[q] = -INFINITY; ti[q] = INT_MAX; }
        for (int j = 0; j < 32; ++j) {
            const int e = sub + (j << 3);    // ascending index => stable
            const float v = sc[row * NEXP + e] + bias[e];
            if (v > tv[TOPK - 1]) {
                int p = TOPK - 1;
                while (p > 0 && v > tv[p - 1]) {
                    tv[p] = tv[p - 1]; ti[p] = ti[p - 1]; --p;
                }
                tv[p] = v; ti[p] = e;
            }
        }
#pragma unroll
        for (int q = 0; q < TOPK; ++q) {
            cval[row * 64 + sub * 8 + q] = tv[q];
            cidx[row * 64 + sub * 8 + q] = ti[q];
        }
    }
    __syncthreads();

    // ---- leaders merge 8 sorted lists; ties -> lower index; output ----
    if (tid < 128 && (tid & 7) == 0) {
        const int row = tid >> 3;
        int p[8];
#pragma unroll
        for (int s = 0; s < 8; ++s) p[s] = 0;
        float g[TOPK];
        int   sel[TOPK];
        for (int k = 0; k < TOPK; ++k) {
            float best = -INFINITY;
            int bidx = INT_MAX;
            int bs = 0;
            for (int s = 0; s < 8; ++s) {
                if (p[s] < 8) {
                    const float v = cval[row * 64 + s * 8 + p[s]];
                    const int  id = cidx[row * 64 + s * 8 + p[s]];
                    if (v > best || (v == best && id < bidx)) {
                        best = v; bidx = id; bs = s;
                    }
                }
            }
            p[bs]++;
            sel[k] = bidx;
            g[k] = sc[row * NEXP + bidx];    // original score (no bias)
        }
        const float s01 = g[0] + g[1], s23 = g[2] + g[3];
        const float s45 = g[4] + g[5], s67 = g[6] + g[7];
        const float wsum = (s01 + s23) + (s45 + s67);
        const float den = wsum + 1e-20f;
        const size_t orow = (size_t)(gr + row) * TOPK;
#pragma unroll
        for (int k = 0; k < TOPK; ++k) {
            outw[orow + k] = (g[k] / den) * 2.5f;
            outi[orow + k] = (float)sel[k];
        }
    }
}

extern "C" void kernel_launch(void* const* d_in, const int* in_sizes, int n_in,
                              void* d_out, int out_size, void* d_ws, size_t ws_size,
                              hipStream_t stream) {
    const float* x    = (const float*)d_in[0];
    const float* w    = (const float*)d_in[1];
    const float* bias = (const float*)d_in[2];
    float* outw = (float*)d_out;
    const int M = in_sizes[0] / DIM;              // 16384 rows
    float* outi = outw + (size_t)M * TOPK;
    const int grid = M / BM;                      // 1024 blocks
    hipLaunchKernelGGL(gate_kernel, dim3(grid), dim3(NTH), 0, stream,
                       x, w, bias, outw, outi);
}